// Round 13
// baseline (758.376 us; speedup 1.0000x reference)
//
#include <hip/hip_runtime.h>
#include <hip/hip_bf16.h>
#include <hip/hip_fp8.h>

// ---------- types ----------
typedef __attribute__((ext_vector_type(4))) float  f32x4;
typedef __attribute__((ext_vector_type(8))) unsigned short u16x8;
typedef long long f8x8;   // 8 fp8 in 2 VGPRs (MFMA fp8 operand)

#define DIM 384
#define NE 8
#define HID 1536
#define NB 32
#define HW 1024
#define T_TOK 32768  // NB*HW
#define LCAP 12288   // per-expert list capacity (mean 8192, +50 sigma)

__device__ __forceinline__ unsigned short f2bf(float f) {
    unsigned int u = __float_as_uint(f);
    u = (u + 0x7fffu + ((u >> 16) & 1u)) >> 16;
    return (unsigned short)u;
}
__device__ __forceinline__ float bf2f(unsigned short u) {
    return __uint_as_float((unsigned int)u << 16);
}
__device__ __forceinline__ unsigned char f2fp8(float f) {
    __hip_fp8_e4m3 h(f);
    return (unsigned char)h.__x;
}
__device__ __forceinline__ float fp82f(unsigned int b) {
    __hip_fp8_e4m3 h; h.__x = (unsigned char)b; return (float)h;
}
__device__ __forceinline__ float gelu_f(float v) {
    float zz = v * fmaf(v * v, -0.07135481627f, -1.5957691216f); // = -2z
    return v * __builtin_amdgcn_rcpf(1.f + __expf(zz));
}
__device__ __forceinline__ unsigned int pk4_fp8(float a, float b, float c, float d) {
#if __has_builtin(__builtin_amdgcn_cvt_pk_fp8_f32)
    int v = __builtin_amdgcn_cvt_pk_fp8_f32(a, b, 0, false);
    v = __builtin_amdgcn_cvt_pk_fp8_f32(c, d, v, true);
    return (unsigned int)v;
#else
    return (unsigned int)f2fp8(a) | ((unsigned int)f2fp8(b) << 8) |
           ((unsigned int)f2fp8(c) << 16) | ((unsigned int)f2fp8(d) << 24);
#endif
}

// ---------- K0: transpose fp32 [E][R][C] -> fp8 [E][C][R] ----------
__global__ __launch_bounds__(256) void k_transpose8(const float* __restrict__ src,
                                                    unsigned char* __restrict__ dst,
                                                    int R, int C) {
    int b = blockIdx.x;
    int ctiles = C >> 5;
    int rtiles = R >> 5;
    int ct = b % ctiles;
    int rt = (b / ctiles) % rtiles;
    int e  = b / (ctiles * rtiles);
    __shared__ float t[32][33];
    int tid = threadIdx.x;
    const float* s = src + (size_t)e * R * C;
    unsigned char* d = dst + (size_t)e * C * R;
#pragma unroll
    for (int k = 0; k < 4; ++k) {
        int idx = k * 256 + tid;
        int rr = idx >> 5, cc = idx & 31;
        t[rr][cc] = s[(size_t)(rt * 32 + rr) * C + ct * 32 + cc];
    }
    __syncthreads();
    int cc = tid >> 3, r4 = tid & 7;
    unsigned int pk = pk4_fp8(t[r4 * 4 + 0][cc], t[r4 * 4 + 1][cc],
                              t[r4 * 4 + 2][cc], t[r4 * 4 + 3][cc]);
    *(unsigned int*)&d[(size_t)(ct * 32 + cc) * R + rt * 32 + r4 * 4] = pk;
}

// ---------- K1: depthwise 7x7 conv, NCHW -> NCHW (xconv fp8) ----------
__global__ __launch_bounds__(256) void k_conv(const float* __restrict__ in,
                                              const float* __restrict__ dw_w,
                                              const float* __restrict__ dw_b,
                                              unsigned char* __restrict__ xconv) {
    int nc = blockIdx.x;             // n*384 + c
    int c = nc % DIM;
    __shared__ float tile[38 * 38];
    __shared__ float wt[49];
    const float* plane = in + (size_t)nc * HW;
    int tid = threadIdx.x;
    if (tid < 49) wt[tid] = dw_w[c * 49 + tid];
    for (int idx = tid; idx < 38 * 38; idx += 256) {
        int ty = idx / 38, tx = idx % 38;
        int ih = ty - 3, iw = tx - 3;
        float v = 0.f;
        if ((unsigned)ih < 32u && (unsigned)iw < 32u) v = plane[ih * 32 + iw];
        tile[idx] = v;
    }
    __syncthreads();
    float bias = dw_b[c];
    int w = tid & 31, h0 = (tid >> 5) << 2;   // 4 consecutive h rows per thread
    float acc[4] = {bias, bias, bias, bias};
#pragma unroll
    for (int iy = 0; iy < 10; ++iy) {
        float r[7];
#pragma unroll
        for (int dx = 0; dx < 7; ++dx) r[dx] = tile[(h0 + iy) * 38 + w + dx];
#pragma unroll
        for (int o = 0; o < 4; ++o) {
            int dy = iy - o;
            if (dy >= 0 && dy < 7) {
                float a = 0.f;
#pragma unroll
                for (int dx = 0; dx < 7; ++dx) a += r[dx] * wt[dy * 7 + dx];
                acc[o] += a;
            }
        }
    }
    unsigned char* outp = xconv + (size_t)nc * HW;
#pragma unroll
    for (int o = 0; o < 4; ++o) outp[(h0 + o) * 32 + w] = f2fp8(acc[o]);
}

// ---------- K2: LayerNorm + gate + top-2 routing (fp8 in/out, packed lists) ----------
__global__ __launch_bounds__(256) void k_ln_gate(const unsigned char* __restrict__ xconv,
                                                 const float* __restrict__ ln_g,
                                                 const float* __restrict__ ln_b,
                                                 const float* __restrict__ gate_w,
                                                 unsigned char* __restrict__ lnout,
                                                 int* __restrict__ lists,
                                                 int* __restrict__ counts) {
    __shared__ float xs[32][385];
    __shared__ float gw[8][384];
    __shared__ float gls[384], bls[384];
    __shared__ int hcnt[8], hbase[8];
    __shared__ int lexp[32][2];
    __shared__ int lpos[32][2];
    __shared__ float lw[32][2];

    int b = blockIdx.x;
    int n = b >> 5;
    int hw0 = (b & 31) << 5;
    int tid = threadIdx.x;

    for (int i = tid; i < 384; i += 256) { gls[i] = ln_g[i]; bls[i] = ln_b[i]; }
    for (int i = tid; i < 8 * 384; i += 256) gw[i / 384][i % 384] = gate_w[i];
    if (tid < 8) hcnt[tid] = 0;

    const unsigned char* base = xconv + (size_t)n * DIM * HW + hw0;
#pragma unroll
    for (int k = 0; k < 48; ++k) {
        int idx = k * 256 + tid;
        int c = idx >> 5, j = idx & 31;
        xs[j][c] = fp82f(base[(size_t)c * HW + j]);
    }
    __syncthreads();

    int tok = tid >> 3, jj = tid & 7;     // 8 lanes per token
    float sum = 0.f, sq = 0.f;
#pragma unroll
    for (int k = 0; k < 48; ++k) {
        float v = xs[tok][jj + 8 * k];
        sum += v; sq += v * v;
    }
#pragma unroll
    for (int m = 1; m < 8; m <<= 1) { sum += __shfl_xor(sum, m); sq += __shfl_xor(sq, m); }
    float mu = sum * (1.f / 384.f);
    float var = sq * (1.f / 384.f) - mu * mu;
    float rstd = rsqrtf(var + 1e-6f);

    int tglob = n * HW + hw0 + tok;
    float p[8] = {0, 0, 0, 0, 0, 0, 0, 0};
#pragma unroll
    for (int k = 0; k < 48; ++k) {
        int c = jj + 8 * k;
        float v = (xs[tok][c] - mu) * rstd * gls[c] + bls[c];
        lnout[(size_t)tglob * DIM + c] = f2fp8(v);
#pragma unroll
        for (int e = 0; e < 8; ++e) p[e] += v * gw[e][c];
    }
#pragma unroll
    for (int e = 0; e < 8; ++e)
#pragma unroll
        for (int m = 1; m < 8; m <<= 1) p[e] += __shfl_xor(p[e], m);

    if (jj == 0) {
        int i0 = 0; float v0 = p[0];
#pragma unroll
        for (int e = 1; e < 8; ++e) if (p[e] > v0) { v0 = p[e]; i0 = e; }
        int i1 = -1; float v1 = -1e30f;
#pragma unroll
        for (int e = 0; e < 8; ++e) if (e != i0 && p[e] > v1) { v1 = p[e]; i1 = e; }
        float w0 = 1.f / (1.f + __expf(v1 - v0));
        float w1 = 1.f - w0;
        lexp[tok][0] = i0; lexp[tok][1] = i1;
        lw[tok][0] = w0;  lw[tok][1] = w1;
        lpos[tok][0] = atomicAdd(&hcnt[i0], 1);
        lpos[tok][1] = atomicAdd(&hcnt[i1], 1);
    }
    __syncthreads();
    if (tid < 8) hbase[tid] = atomicAdd(&counts[tid], hcnt[tid]);
    __syncthreads();
    if (jj == 0) {
#pragma unroll
        for (int s = 0; s < 2; ++s) {
            int e = lexp[tok][s];
            int pos = hbase[e] + lpos[tok][s];
            if (pos < LCAP)
                lists[e * LCAP + pos] = ((unsigned int)f2bf(lw[tok][s]) << 16)
                                      | (unsigned int)((tglob << 1) | s);
        }
    }
}

// ---------- K3a: H = gelu(X @ W1 + b1) -> Hbuf[ent][1536] fp8 ----------
// Barrier-free main loop: X staged once to LDS (one barrier), then each wave
// streams W1 from L2 and stores H directly to global. No producer-consumer sync.
__global__ __launch_bounds__(512, 2) void k_h(const unsigned char* __restrict__ ln,
                                              const unsigned char* __restrict__ w1t, // [8][1536][384] fp8
                                              const float* __restrict__ b1,
                                              const int* __restrict__ lists,
                                              const int* __restrict__ counts,
                                              unsigned char* __restrict__ Hbuf) {
    int e    = blockIdx.x & 7;        // expert -> fixed XCD
    int tile = blockIdx.x >> 3;       // 0..95, BM=128
    int cnt = counts[e]; if (cnt > LCAP) cnt = LCAP;
    if (tile * 128 >= cnt) return;

    __shared__ unsigned char X[128][400];
    __shared__ int ents[128];
    int tid = threadIdx.x;
    if (tid < 128) {
        int idx = tile * 128 + tid;
        ents[tid] = (idx < cnt) ? (lists[e * LCAP + idx] & 0xFFFF) : -1;
    }
    __syncthreads();
    {
        int row = tid >> 2, q = tid & 3;
        int ent = ents[row];
        int tok = (ent < 0) ? 0 : (ent >> 1);
        const u16x8* src = (const u16x8*)(ln + (size_t)tok * DIM);
#pragma unroll
        for (int r = 0; r < 6; ++r)
            *(u16x8*)&X[row][(q + r * 4) * 16] = __builtin_nontemporal_load(&src[q + r * 4]);
    }
    __syncthreads();   // the only barrier; main loop below is sync-free

    int w = tid >> 6, lane = tid & 63;
    int lr = lane & 15, lq = lane >> 4;

    const unsigned char* pa = w1t + ((size_t)e * HID + w * 192 + lr) * DIM + lq * 8;
    const float* pb = b1 + e * HID + w * 192 + lq * 4;
    int entm[8];
#pragma unroll
    for (int m = 0; m < 8; ++m) entm[m] = ents[m * 16 + lr];

    for (int c = 0; c < 12; ++c) {       // wave's 192-hid strip in 16-hid chunks
        const unsigned char* pac = pa + (size_t)c * 16 * DIM;
        f32x4 bv = *(const f32x4*)(pb + c * 16);
        f32x4 Hf[8];
#pragma unroll
        for (int m = 0; m < 8; ++m) Hf[m] = bv;
#pragma unroll
        for (int k = 0; k < 12; ++k) {
            f8x8 wf = *(const f8x8*)(pac + k * 32);
            f8x8 a0 = *(const f8x8*)&X[ 0 + lr][k * 32 + lq * 8];
            f8x8 a1 = *(const f8x8*)&X[16 + lr][k * 32 + lq * 8];
            f8x8 a2 = *(const f8x8*)&X[32 + lr][k * 32 + lq * 8];
            f8x8 a3 = *(const f8x8*)&X[48 + lr][k * 32 + lq * 8];
            f8x8 a4 = *(const f8x8*)&X[64 + lr][k * 32 + lq * 8];
            f8x8 a5 = *(const f8x8*)&X[80 + lr][k * 32 + lq * 8];
            f8x8 a6 = *(const f8x8*)&X[96 + lr][k * 32 + lq * 8];
            f8x8 a7 = *(const f8x8*)&X[112 + lr][k * 32 + lq * 8];
            Hf[0] = __builtin_amdgcn_mfma_f32_16x16x32_fp8_fp8(wf, a0, Hf[0], 0, 0, 0);
            Hf[1] = __builtin_amdgcn_mfma_f32_16x16x32_fp8_fp8(wf, a1, Hf[1], 0, 0, 0);
            Hf[2] = __builtin_amdgcn_mfma_f32_16x16x32_fp8_fp8(wf, a2, Hf[2], 0, 0, 0);
            Hf[3] = __builtin_amdgcn_mfma_f32_16x16x32_fp8_fp8(wf, a3, Hf[3], 0, 0, 0);
            Hf[4] = __builtin_amdgcn_mfma_f32_16x16x32_fp8_fp8(wf, a4, Hf[4], 0, 0, 0);
            Hf[5] = __builtin_amdgcn_mfma_f32_16x16x32_fp8_fp8(wf, a5, Hf[5], 0, 0, 0);
            Hf[6] = __builtin_amdgcn_mfma_f32_16x16x32_fp8_fp8(wf, a6, Hf[6], 0, 0, 0);
            Hf[7] = __builtin_amdgcn_mfma_f32_16x16x32_fp8_fp8(wf, a7, Hf[7], 0, 0, 0);
        }
        int col = w * 192 + c * 16 + lq * 4;
#pragma unroll
        for (int m = 0; m < 8; ++m) {
            if (entm[m] >= 0) {
                unsigned int pk = pk4_fp8(gelu_f(Hf[m][0]), gelu_f(Hf[m][1]),
                                          gelu_f(Hf[m][2]), gelu_f(Hf[m][3]));
                *(unsigned int*)&Hbuf[(size_t)entm[m] * HID + col] = pk;
            }
        }
    }
}

// ---------- K3b: Y = (H @ W2 + b2) * gate_w -> y0/y1 fp8 ----------
// Zero LDS, zero barriers: H-frags gathered from global/L2, W2 from L2.
__global__ __launch_bounds__(512, 2) void k_y(const unsigned char* __restrict__ Hbuf,
                                              const unsigned char* __restrict__ w2t, // [8][384][1536] fp8
                                              const float* __restrict__ b2,
                                              const int* __restrict__ lists,
                                              const int* __restrict__ counts,
                                              unsigned char* __restrict__ y0,
                                              unsigned char* __restrict__ y1) {
    int e    = blockIdx.x & 7;
    int tile = blockIdx.x >> 3;       // 0..191, BM=64
    int cnt = counts[e]; if (cnt > LCAP) cnt = LCAP;
    if (tile * 64 >= cnt) return;

    int tid = threadIdx.x;
    int w = tid >> 6, lane = tid & 63;
    int lr = lane & 15, lq = lane >> 4;

    int entm[4]; float wvm[4];
#pragma unroll
    for (int m = 0; m < 4; ++m) {
        int idx = tile * 64 + m * 16 + lr;
        if (idx < cnt) {
            int v = lists[e * LCAP + idx];
            entm[m] = v & 0xFFFF;
            wvm[m] = bf2f((unsigned short)((unsigned int)v >> 16));
        } else { entm[m] = -1; wvm[m] = 0.f; }
    }
    unsigned int hoff[4];
#pragma unroll
    for (int m = 0; m < 4; ++m)
        hoff[m] = (unsigned int)((entm[m] < 0 ? 0 : entm[m]) * HID) + (unsigned int)(lq * 8);

    const unsigned char* q2 = w2t + ((size_t)e * DIM + w * 48 + lr) * HID + lq * 8;
    f32x4 Yacc[3][4] = {};   // [nj][m]: dims w*48+nj*16+lq*4+i, token m*16+lr

#pragma unroll 4
    for (int k2 = 0; k2 < 48; ++k2) {
        f8x8 wf0 = *(const f8x8*)(q2 + k2 * 32);
        f8x8 wf1 = *(const f8x8*)(q2 + (size_t)16 * HID + k2 * 32);
        f8x8 wf2 = *(const f8x8*)(q2 + (size_t)32 * HID + k2 * 32);
#pragma unroll
        for (int m = 0; m < 4; ++m) {
            f8x8 h = *(const f8x8*)(Hbuf + hoff[m] + k2 * 32);
            Yacc[0][m] = __builtin_amdgcn_mfma_f32_16x16x32_fp8_fp8(wf0, h, Yacc[0][m], 0, 0, 0);
            Yacc[1][m] = __builtin_amdgcn_mfma_f32_16x16x32_fp8_fp8(wf1, h, Yacc[1][m], 0, 0, 0);
            Yacc[2][m] = __builtin_amdgcn_mfma_f32_16x16x32_fp8_fp8(wf2, h, Yacc[2][m], 0, 0, 0);
        }
    }

    f32x4 b2v[3];
#pragma unroll
    for (int nj = 0; nj < 3; ++nj)
        b2v[nj] = *(const f32x4*)&b2[e * DIM + w * 48 + nj * 16 + lq * 4];
#pragma unroll
    for (int m = 0; m < 4; ++m) {
        if (entm[m] >= 0) {
            float wv = wvm[m];
            int tok = entm[m] >> 1;
            unsigned char* yb = (entm[m] & 1) ? y1 : y0;
#pragma unroll
            for (int nj = 0; nj < 3; ++nj) {
                unsigned int pk = pk4_fp8((Yacc[nj][m][0] + b2v[nj][0]) * wv,
                                          (Yacc[nj][m][1] + b2v[nj][1]) * wv,
                                          (Yacc[nj][m][2] + b2v[nj][2]) * wv,
                                          (Yacc[nj][m][3] + b2v[nj][3]) * wv);
                *(unsigned int*)(yb + (size_t)tok * DIM + w * 48 + nj * 16 + lq * 4) = pk;
            }
        }
    }
}

// ---------- K4: out = input + layer_scale[c] * (y0 + y1), NHWC->NCHW ----------
__global__ __launch_bounds__(256) void k_final(const float* __restrict__ input,
                                               const float* __restrict__ ls,
                                               const unsigned char* __restrict__ y0,
                                               const unsigned char* __restrict__ y1,
                                               float* __restrict__ out) {
    int b = blockIdx.x;
    int ct = b % 12;
    int hwt = (b / 12) % 32;
    int n = b / (12 * 32);
    int c0 = ct * 32, hw0 = hwt * 32;
    __shared__ float t[32][33];
    int tid = threadIdx.x;
    int t0 = n * HW + hw0;
    {
        int tl = tid >> 3, q = tid & 7;     // 32 tokens x 8 channel-quads
        size_t o = (size_t)(t0 + tl) * DIM + c0 + q * 4;
        unsigned int a = *(const unsigned int*)(y0 + o);
        unsigned int c = *(const unsigned int*)(y1 + o);
#pragma unroll
        for (int i = 0; i < 4; ++i)
            t[tl][q * 4 + i] = fp82f((a >> (8 * i)) & 0xFFu) + fp82f((c >> (8 * i)) & 0xFFu);
    }
    __syncthreads();
#pragma unroll
    for (int k = 0; k < 4; ++k) {
        int idx = k * 256 + tid;
        int cl = idx >> 5, j = idx & 31;
        size_t o = ((size_t)n * DIM + c0 + cl) * HW + hw0 + j;
        out[o] = input[o] + ls[c0 + cl] * t[j][cl];
    }
}

// ---------- launch ----------
extern "C" void kernel_launch(void* const* d_in, const int* in_sizes, int n_in,
                              void* d_out, int out_size, void* d_ws, size_t ws_size,
                              hipStream_t stream) {
    const float* input  = (const float*)d_in[0];
    const float* dw_w   = (const float*)d_in[1];
    const float* dw_b   = (const float*)d_in[2];
    const float* ln_g   = (const float*)d_in[3];
    const float* ln_b   = (const float*)d_in[4];
    const float* gate_w = (const float*)d_in[5];
    const float* w1     = (const float*)d_in[6];
    const float* b1     = (const float*)d_in[7];
    const float* w2     = (const float*)d_in[8];
    const float* b2     = (const float*)d_in[9];
    const float* lscale = (const float*)d_in[10];

    // ws layout (bytes); xconv/lnb fp8 are overlaid by y0/y1 fp8 after k_h.
    const size_t SZ_T8 = (size_t)T_TOK * DIM;     // 12,582,912 (fp8 per-token plane)
    const size_t SZ_H  = (size_t)2 * T_TOK * HID; // 100,663,296 (H fp8, ent-indexed)
    const size_t SZ_W  = (size_t)NE * DIM * HID;  //   4,718,592 (fp8 weights)
    char* ws = (char*)d_ws;
    unsigned char* xconv = (unsigned char*)(ws + 0);            // dead after ln_gate
    unsigned char* lnb   = (unsigned char*)(ws + SZ_T8);        // dead after k_h
    unsigned char* y0    = (unsigned char*)(ws + 0);            // overlays xconv
    unsigned char* y1    = (unsigned char*)(ws + SZ_T8);        // overlays lnb
    unsigned char* Hbuf  = (unsigned char*)(ws + 2 * SZ_T8);
    unsigned char* w1t   = (unsigned char*)(ws + 2 * SZ_T8 + SZ_H);
    unsigned char* w2t   = (unsigned char*)(ws + 2 * SZ_T8 + SZ_H + SZ_W);
    int* lists           = (int*)(ws + 2 * SZ_T8 + SZ_H + 2 * SZ_W);
    int* counts          = (int*)(ws + 2 * SZ_T8 + SZ_H + 2 * SZ_W + (size_t)NE * LCAP * 4);
    const size_t needed  = 2 * SZ_T8 + SZ_H + 2 * SZ_W + (size_t)NE * LCAP * 4 + 256;
    if (ws_size < needed) return;   // visible failure if ws too small

    hipMemsetAsync(counts, 0, 32, stream);
    k_transpose8<<<8 * 12 * 48, 256, 0, stream>>>(w1, w1t, DIM, HID);
    k_transpose8<<<8 * 48 * 12, 256, 0, stream>>>(w2, w2t, HID, DIM);
    k_conv<<<NB * DIM, 256, 0, stream>>>(input, dw_w, dw_b, xconv);
    k_ln_gate<<<T_TOK / 32, 256, 0, stream>>>(xconv, ln_g, ln_b, gate_w, lnb, lists, counts);
    k_h<<<NE * (LCAP / 128), 512, 0, stream>>>(lnb, w1t, b1, lists, counts, Hbuf);
    k_y<<<NE * (LCAP / 64), 512, 0, stream>>>(Hbuf, w2t, b2, lists, counts, y0, y1);
    k_final<<<NB * 32 * 12, 256, 0, stream>>>(input, lscale, y0, y1, (float*)d_out);
}